// Round 10
// baseline (192.002 us; speedup 1.0000x reference)
//
#include <hip/hip_runtime.h>
#include <hip/hip_bf16.h>
#include <math.h>

// Problem constants
constexpr int Bsz = 4, T = 2048, Hh = 8;
constexpr int HFi = 64, WFi = 64;
constexpr float RADIUS = 0.08f;

typedef __bf16 bf16x8 __attribute__((ext_vector_type(8)));
typedef float f32x4 __attribute__((ext_vector_type(4)));
typedef unsigned short u16x8 __attribute__((ext_vector_type(8)));

typedef const __attribute__((address_space(1))) void* gcptr;
typedef __attribute__((address_space(3))) void* lptr;

#define GLOAD_LDS16(g, l) \
  __builtin_amdgcn_global_load_lds((gcptr)(const void*)(g), (lptr)(void*)(l), 16, 0, 0)

union BU { __hip_bfloat16 b; unsigned short u; };

__device__ __forceinline__ float bflo(unsigned int u) {
  return __uint_as_float(u << 16);
}
__device__ __forceinline__ float bfhi(unsigned int u) {
  return __uint_as_float(u & 0xffff0000u);
}

// ---------------------------------------------------------------------------
// Combined prep kernel (one dispatch for all input conditioning):
//  blocks [0,4096):     split q into hi/lo bf16 (qsplit[m][0:512]=hi,[512:1024]=lo)
//  blocks [4096,6400):  build Wcat (384x1536 B^T = [W_hi|W_hi|W_lo]) + bias_cat
//  blocks [6400,6528):  transpose Wv -> WvT, W_out -> WoutT (64x64 tiles)
//  blocks [6528,8576):  transpose fmap (B,512,4096) -> fmapT (B,4096,512) bf16
// ---------------------------------------------------------------------------
__global__ __launch_bounds__(256) void prep_kernel(
    const float* __restrict__ q, __hip_bfloat16* __restrict__ qsplit,
    const float* __restrict__ W_off, const float* __restrict__ W_w,
    const float* __restrict__ b_off, const float* __restrict__ b_w,
    __hip_bfloat16* __restrict__ Wcat, float* __restrict__ bias_cat,
    const float* __restrict__ Wv, __hip_bfloat16* __restrict__ WvT,
    const float* __restrict__ W_out, __hip_bfloat16* __restrict__ WoutT,
    const float* __restrict__ fmap, __hip_bfloat16* __restrict__ fmapT) {
  __shared__ float tile[64][65];
  const int blk = blockIdx.x;
  const int tid = threadIdx.x;
  if (blk < 4096) {
    const int idx = blk * 256 + tid;  // 8192*128
    const int m = idx >> 7, kq = (idx & 127) * 4;
    float4 v = *(const float4*)&q[(size_t)m * 512 + kq];
    union { __hip_bfloat16 b[4]; ushort4 u; } hi, lo;
    float f[4] = {v.x, v.y, v.z, v.w};
#pragma unroll
    for (int i = 0; i < 4; ++i) {
      hi.b[i] = __float2bfloat16(f[i]);
      lo.b[i] = __float2bfloat16(f[i] - __bfloat162float(hi.b[i]));
    }
    *(ushort4*)&qsplit[(size_t)m * 1024 + kq] = hi.u;
    *(ushort4*)&qsplit[(size_t)m * 1024 + 512 + kq] = lo.u;
    return;
  }
  if (blk < 6400) {
    const int idx = (blk - 4096) * 256 + tid;  // 384*1536 = 589824
    const int n = idx / 1536, kp = idx % 1536;
    const int k = kp & 511;
    const float w = (n < 256) ? W_off[(size_t)k * 256 + n]
                              : W_w[(size_t)k * 128 + (n - 256)];
    const __hip_bfloat16 h = __float2bfloat16(w);
    const __hip_bfloat16 o =
        (kp < 1024) ? h : __float2bfloat16(w - __bfloat162float(h));
    Wcat[(size_t)n * 1536 + kp] = o;
    if (idx < 384) bias_cat[idx] = (idx < 256) ? b_off[idx] : b_w[idx - 256];
    return;
  }
  // --- 64x64 transpose segments ---
  const float* src;
  __hip_bfloat16* dst;
  int ldin, ldout, r0, c0;
  if (blk < 6528) {
    const int t2 = blk - 6400;  // 0..127
    src = (t2 < 64) ? Wv : W_out;
    dst = (t2 < 64) ? WvT : WoutT;
    ldin = 512; ldout = 512;
    const int tl = t2 & 63;
    r0 = (tl >> 3) * 64; c0 = (tl & 7) * 64;
  } else {
    const int t3 = blk - 6528;          // 0..2047
    const int b = t3 >> 9;              // 512 tiles per batch
    const int tl = t3 & 511;
    r0 = (tl >> 6) * 64;                // channel rows
    c0 = (tl & 63) * 64;                // spatial cols
    src = fmap + (size_t)b * 512 * 4096;
    dst = fmapT + (size_t)b * 4096 * 512;
    ldin = 4096; ldout = 512;
  }
  {
    const int tr = tid >> 2;          // 0..63 input row
    const int tc = (tid & 3) * 16;    // input col chunk
    const float* s = &src[(size_t)(r0 + tr) * ldin + c0 + tc];
#pragma unroll
    for (int j4 = 0; j4 < 4; ++j4) {
      float4 v = *(const float4*)&s[j4 * 4];
      tile[tr][tc + j4 * 4 + 0] = v.x;
      tile[tr][tc + j4 * 4 + 1] = v.y;
      tile[tr][tc + j4 * 4 + 2] = v.z;
      tile[tr][tc + j4 * 4 + 3] = v.w;
    }
    __syncthreads();
    const int oc = tid >> 2;          // output row offset (= input col)
    const int rb = (tid & 3) * 16;    // output col chunk (= input rows)
    u16x8 o0, o1;
#pragma unroll
    for (int j = 0; j < 8; ++j) {
      BU a, bz;
      a.b = __float2bfloat16(tile[rb + j][oc]);
      bz.b = __float2bfloat16(tile[rb + 8 + j][oc]);
      o0[j] = a.u;
      o1[j] = bz.u;
    }
    __hip_bfloat16* d = &dst[(size_t)(c0 + oc) * ldout + r0 + rb];
    *(u16x8*)d = o0;
    *(u16x8*)(d + 8) = o1;
  }
}

// ---------------------------------------------------------------------------
// Fused GEMM dispatch (unchanged from round 9 — swizzle verified).
//  blocks [0,384):   offset/logit projection, 128x64 tile, K=1536 split-bf16.
//  blocks [384,896): value projection, 128x128 tile, per-batch, C retiled
//                    through LDS -> coalesced bf16 stores to vflat.
// ---------------------------------------------------------------------------
__global__ __launch_bounds__(256) void fused_gemm(
    const __hip_bfloat16* __restrict__ qsplit,
    const __hip_bfloat16* __restrict__ Wcat,
    const float* __restrict__ bias_cat, float* __restrict__ projbuf,
    const __hip_bfloat16* __restrict__ fmapT,
    const __hip_bfloat16* __restrict__ WvT, __hip_bfloat16* __restrict__ vflat) {
  __shared__ unsigned short lds[2 * 128 * 64];  // As | Bs ; reused as C-tile
  unsigned short* As = lds;
  unsigned short* Bs = lds + 128 * 64;
  const int blk = blockIdx.x;
  const int tid = threadIdx.x;
  const int lane = tid & 63;
  const int wave = tid >> 6;
  const int l15 = lane & 15, quad = lane >> 4;
  const int srow = lane >> 3;                   // 0..7
  const int scol = (((lane & 7) ^ srow) * 8);   // swizzled source col (elems)
  const int fxor = (l15 & 7) * 8;               // fragment-read XOR (elems)

  if (blk < 384) {
    // ---- projection GEMM: 128x64, K=1536 ----
    const int m0 = (blk & 63) * 128;
    const int n0 = (blk >> 6) * 64;
    const int wm = (wave & 1) * 64, wn = (wave >> 1) * 32;
    f32x4 acc[4][2] = {};
    for (int k0 = 0; k0 < 1536; k0 += 64) {
      const int ka = (k0 >= 1024) ? k0 - 1024 : k0;
#pragma unroll
      for (int i = 0; i < 4; ++i) {
        const int j = wave * 4 + i;
        const int r = j * 8 + srow;
        GLOAD_LDS16(qsplit + (size_t)(m0 + r) * 1024 + ka + scol, As + j * 512);
      }
#pragma unroll
      for (int i = 0; i < 2; ++i) {
        const int j = wave * 2 + i;
        const int r = j * 8 + srow;
        GLOAD_LDS16(Wcat + (size_t)(n0 + r) * 1536 + k0 + scol, Bs + j * 512);
      }
      __syncthreads();
#pragma unroll
      for (int ks = 0; ks < 2; ++ks) {
        bf16x8 af[4], bfr[2];
#pragma unroll
        for (int i = 0; i < 4; ++i)
          af[i] = *(const bf16x8*)&As[(wm + i * 16 + l15) * 64 + ((ks * 32 + quad * 8) ^ fxor)];
#pragma unroll
        for (int j = 0; j < 2; ++j)
          bfr[j] = *(const bf16x8*)&Bs[(wn + j * 16 + l15) * 64 + ((ks * 32 + quad * 8) ^ fxor)];
#pragma unroll
        for (int i = 0; i < 4; ++i)
#pragma unroll
          for (int j = 0; j < 2; ++j)
            acc[i][j] = __builtin_amdgcn_mfma_f32_16x16x32_bf16(af[i], bfr[j], acc[i][j], 0, 0, 0);
      }
      __syncthreads();
    }
#pragma unroll
    for (int i = 0; i < 4; ++i) {
      const int mbase = m0 + wm + i * 16 + quad * 4;
#pragma unroll
      for (int j = 0; j < 2; ++j) {
        const int n = n0 + wn + j * 16 + l15;
        const float bb = bias_cat[n];
#pragma unroll
        for (int r = 0; r < 4; ++r)
          projbuf[(size_t)(mbase + r) * 384 + n] = acc[i][j][r] + bb;
      }
    }
  } else {
    // ---- value projection GEMM: 128x128, K=512 ----
    const int vb = blk - 384;
    const int b = vb >> 7, rr = vb & 127;
    const int m0 = (rr >> 2) * 128;
    const int n0 = (rr & 3) * 128;
    const __hip_bfloat16* A = fmapT + (size_t)b * 4096 * 512;
    __hip_bfloat16* vout = vflat + (size_t)b * 8 * 4096 * 64;
    const int wm = (wave & 1) * 64, wn = (wave >> 1) * 64;
    f32x4 acc[4][4] = {};
    for (int k0 = 0; k0 < 512; k0 += 64) {
#pragma unroll
      for (int i = 0; i < 4; ++i) {
        const int j = wave * 4 + i;
        const int r = j * 8 + srow;
        GLOAD_LDS16(A + (size_t)(m0 + r) * 512 + k0 + scol, As + j * 512);
        GLOAD_LDS16(WvT + (size_t)(n0 + r) * 512 + k0 + scol, Bs + j * 512);
      }
      __syncthreads();
#pragma unroll
      for (int ks = 0; ks < 2; ++ks) {
        bf16x8 af[4], bfr[4];
#pragma unroll
        for (int i = 0; i < 4; ++i)
          af[i] = *(const bf16x8*)&As[(wm + i * 16 + l15) * 64 + ((ks * 32 + quad * 8) ^ fxor)];
#pragma unroll
        for (int j = 0; j < 4; ++j)
          bfr[j] = *(const bf16x8*)&Bs[(wn + j * 16 + l15) * 64 + ((ks * 32 + quad * 8) ^ fxor)];
#pragma unroll
        for (int i = 0; i < 4; ++i)
#pragma unroll
          for (int j = 0; j < 4; ++j)
            acc[i][j] = __builtin_amdgcn_mfma_f32_16x16x32_bf16(af[i], bfr[j], acc[i][j], 0, 0, 0);
      }
      __syncthreads();
    }
    // epilogue: retile C through LDS (swizzled, conflict-free) -> u16x8 stores
    unsigned short* Ct = lds;  // [128][128] bf16
#pragma unroll
    for (int i = 0; i < 4; ++i) {
#pragma unroll
      for (int j = 0; j < 4; ++j) {
        const int ngl = wn + j * 16 + l15;
#pragma unroll
        for (int r = 0; r < 4; ++r) {
          const int sl = wm + i * 16 + quad * 4 + r;
          BU u;
          u.b = __float2bfloat16(acc[i][j][r]);
          Ct[sl * 128 + (ngl ^ (((sl >> 2) & 3) * 16))] = u.u;
        }
      }
    }
    __syncthreads();
#pragma unroll
    for (int c = 0; c < 8; ++c) {
      const int sl = (tid >> 4) + c * 16;
      const int chunk = tid & 15;
      const int head = (n0 >> 6) + (chunk >> 3);
      const int dh = (chunk & 7) * 8;
      const int e = (chunk * 8) ^ (((sl >> 2) & 3) * 16);
      *(u16x8*)(vout + (size_t)head * (4096 * 64) + (size_t)(m0 + sl) * 64 + dh) =
          *(const u16x8*)&Ct[sl * 128 + e];
    }
  }
}

// ---------------------------------------------------------------------------
// Sample v2: wave-per-token. Grid 2048 x 256 (4 waves); wave owns token
// bt = (blk&7)*1024 + (blk>>3)*4 + wave (XCD-contiguous panels).
// Phase A (all lanes): lane = (h = lane>>3, pi = lane&7) computes weights for
// points {pi, pi+8}; softmax via 8-lane shfl_xor reduce (no LDS logits).
// Phase B: 16-lane dh-groups (g = lane>>4, sub = lane&15, dh = 4*sub..+3);
// 4 groups process 4 points per iteration via uint2 loads (4 bf16 each);
// cross-group reduce shfl_xor(16,32); group 0 stores packed uint2 ctx.
// ---------------------------------------------------------------------------
__global__ __launch_bounds__(256) void sample_kernel(
    const float* __restrict__ ref_xy, const float* __restrict__ projbuf,
    const uint2* __restrict__ vflat2, uint2* __restrict__ ctx2) {
  __shared__ float4 wsm[4][8][16];  // {wx0, wx1, wy0*aw, wy1*aw}
  __shared__ int bsm[4][8][16];     // base index in uint2 units: (yA*64+xA)*16
  const int blk = blockIdx.x;
  const int tid = threadIdx.x;
  const int wave = tid >> 6;
  const int lane = tid & 63;
  const int bt = (blk & 7) * 1024 + (blk >> 3) * 4 + wave;
  const int b = bt >> 11;  // T = 2048

  // ---- Phase A: weights (2 points per lane) ----
  {
    const int h = lane >> 3, pi = lane & 7;
    const float ref_x = ref_xy[bt * 2 + 0];
    const float ref_y = ref_xy[bt * 2 + 1];
    const float* prow = projbuf + (size_t)bt * 384;
    const float* lg = prow + 256 + h * 16;
    const float l0 = lg[pi], l1 = lg[pi + 8];
    float mx = fmaxf(l0, l1);
    mx = fmaxf(mx, __shfl_xor(mx, 1, 64));
    mx = fmaxf(mx, __shfl_xor(mx, 2, 64));
    mx = fmaxf(mx, __shfl_xor(mx, 4, 64));
    const float e0 = __expf(l0 - mx), e1 = __expf(l1 - mx);
    float s = e0 + e1;
    s += __shfl_xor(s, 1, 64);
    s += __shfl_xor(s, 2, 64);
    s += __shfl_xor(s, 4, 64);
    const float inv = 1.0f / s;
    const float* of = prow + h * 32;
#pragma unroll
    for (int q = 0; q < 2; ++q) {
      const int p = pi + q * 8;
      const float aw = inv * (q ? e1 : e0);
      const float2 o2 = *(const float2*)&of[p * 2];
      const float ix = (ref_x + RADIUS * o2.x) * (float)(WFi - 1);
      const float iy = (ref_y + RADIUS * o2.y) * (float)(HFi - 1);
      const float ix0f = floorf(ix), iy0f = floorf(iy);
      const float fx = ix - ix0f, fy = iy - iy0f;
      const int ix0 = (int)ix0f, iy0 = (int)iy0f;

      float wx0 = 1.f - fx, wx1 = fx;
      float wy0 = 1.f - fy, wy1 = fy;
      if (ix0 == -1) { wx0 = fx; wx1 = 0.f; }
      if (ix0 == 63) { wx0 = 0.f; wx1 = 1.f - fx; }
      if (ix0 < -1 || ix0 > 63) { wx0 = 0.f; wx1 = 0.f; }
      if (iy0 == -1) { wy0 = fy; wy1 = 0.f; }
      if (iy0 == 63) { wy0 = 0.f; wy1 = 1.f - fy; }
      if (iy0 < -1 || iy0 > 63) { wy0 = 0.f; wy1 = 0.f; }
      const int xA = min(max(ix0, 0), WFi - 2);
      const int yA = min(max(iy0, 0), HFi - 2);

      wsm[wave][h][p] = make_float4(wx0, wx1, wy0 * aw, wy1 * aw);
      bsm[wave][h][p] = (yA * WFi + xA) * 16;  // uint2 units (32 dwords/site)
    }
  }
  __syncthreads();

  // ---- Phase B: gather ----
  const int g = lane >> 4, sub = lane & 15;  // group, dh-quad
#pragma unroll
  for (int h = 0; h < Hh; ++h) {
    const uint2* vb = vflat2 + (size_t)(b * 8 + h) * (4096 * 16) + sub;
    float a0 = 0.f, a1 = 0.f, a2 = 0.f, a3 = 0.f;
#pragma unroll
    for (int it = 0; it < 4; ++it) {
      const int p = g * 4 + it;
      const float4 w4 = wsm[wave][h][p];
      const int base = bsm[wave][h][p];
      const uint2 v00 = vb[base], v10 = vb[base + 16];
      const uint2 v01 = vb[base + 1024], v11 = vb[base + 1040];
      const float w00 = w4.x * w4.z, w10 = w4.y * w4.z;
      const float w01 = w4.x * w4.w, w11 = w4.y * w4.w;

      a0 = fmaf(w00, bflo(v00.x), a0);
      a1 = fmaf(w00, bfhi(v00.x), a1);
      a2 = fmaf(w00, bflo(v00.y), a2);
      a3 = fmaf(w00, bfhi(v00.y), a3);
      a0 = fmaf(w10, bflo(v10.x), a0);
      a1 = fmaf(w10, bfhi(v10.x), a1);
      a2 = fmaf(w10, bflo(v10.y), a2);
      a3 = fmaf(w10, bfhi(v10.y), a3);
      a0 = fmaf(w01, bflo(v01.x), a0);
      a1 = fmaf(w01, bfhi(v01.x), a1);
      a2 = fmaf(w01, bflo(v01.y), a2);
      a3 = fmaf(w01, bfhi(v01.y), a3);
      a0 = fmaf(w11, bflo(v11.x), a0);
      a1 = fmaf(w11, bfhi(v11.x), a1);
      a2 = fmaf(w11, bflo(v11.y), a2);
      a3 = fmaf(w11, bfhi(v11.y), a3);
    }
    // cross-group point reduction (4 groups -> full 16-point sum)
    a0 += __shfl_xor(a0, 16, 64);
    a0 += __shfl_xor(a0, 32, 64);
    a1 += __shfl_xor(a1, 16, 64);
    a1 += __shfl_xor(a1, 32, 64);
    a2 += __shfl_xor(a2, 16, 64);
    a2 += __shfl_xor(a2, 32, 64);
    a3 += __shfl_xor(a3, 16, 64);
    a3 += __shfl_xor(a3, 32, 64);
    if (g == 0) {
      BU c0, c1, c2, c3;
      c0.b = __float2bfloat16(a0);
      c1.b = __float2bfloat16(a1);
      c2.b = __float2bfloat16(a2);
      c3.b = __float2bfloat16(a3);
      uint2 ov;
      ov.x = ((unsigned int)c1.u << 16) | c0.u;
      ov.y = ((unsigned int)c3.u << 16) | c2.u;
      ctx2[(size_t)bt * 128 + h * 16 + sub] = ov;
    }
  }
}

// ---------------------------------------------------------------------------
// Output projection: C[m][n] = sum_k ctx[m*512+k] * WoutT[n*512+k] + b_out[n]
// 128x128 tile, BK=64, global_load_lds(16B) staging, full XOR-swizzled LDS.
// ---------------------------------------------------------------------------
__global__ __launch_bounds__(256) void outproj_kernel(
    const __hip_bfloat16* __restrict__ A, const __hip_bfloat16* __restrict__ Bm,
    const float* __restrict__ bias, float* __restrict__ C) {
  __shared__ unsigned short As[128 * 64];
  __shared__ unsigned short Bs[128 * 64];
  const int tid = threadIdx.x;
  const int lane = tid & 63;
  const int wave = tid >> 6;
  const int wm = (wave & 1) * 64, wn = (wave >> 1) * 64;
  const int l15 = lane & 15, quad = lane >> 4;
  const int m0 = blockIdx.x * 128, n0 = blockIdx.y * 128;
  const int srow = lane >> 3;
  const int scol = (((lane & 7) ^ srow) * 8);
  const int fxor = (l15 & 7) * 8;

  f32x4 acc[4][4] = {};

  for (int k0 = 0; k0 < 512; k0 += 64) {
#pragma unroll
    for (int i = 0; i < 4; ++i) {
      const int j = wave * 4 + i;
      const int r = j * 8 + srow;
      GLOAD_LDS16(A + (size_t)(m0 + r) * 512 + k0 + scol, As + j * 512);
      GLOAD_LDS16(Bm + (size_t)(n0 + r) * 512 + k0 + scol, Bs + j * 512);
    }
    __syncthreads();
#pragma unroll
    for (int ks = 0; ks < 2; ++ks) {
      bf16x8 af[4], bfr[4];
#pragma unroll
      for (int i = 0; i < 4; ++i)
        af[i] = *(const bf16x8*)&As[(wm + i * 16 + l15) * 64 + ((ks * 32 + quad * 8) ^ fxor)];
#pragma unroll
      for (int j = 0; j < 4; ++j)
        bfr[j] = *(const bf16x8*)&Bs[(wn + j * 16 + l15) * 64 + ((ks * 32 + quad * 8) ^ fxor)];
#pragma unroll
      for (int i = 0; i < 4; ++i)
#pragma unroll
        for (int j = 0; j < 4; ++j)
          acc[i][j] = __builtin_amdgcn_mfma_f32_16x16x32_bf16(af[i], bfr[j], acc[i][j], 0, 0, 0);
    }
    __syncthreads();
  }

#pragma unroll
  for (int i = 0; i < 4; ++i) {
    const int mbase = m0 + wm + i * 16 + quad * 4;
#pragma unroll
    for (int j = 0; j < 4; ++j) {
      const int n = n0 + wn + j * 16 + l15;
      const float bb = bias[n];
#pragma unroll
      for (int r = 0; r < 4; ++r)
        C[(size_t)(mbase + r) * 512 + n] = acc[i][j][r] + bb;
    }
  }
}

// ---------------------------------------------------------------------------
extern "C" void kernel_launch(void* const* d_in, const int* in_sizes, int n_in,
                              void* d_out, int out_size, void* d_ws, size_t ws_size,
                              hipStream_t stream) {
  const float* q      = (const float*)d_in[0];
  const float* fmap   = (const float*)d_in[1];
  const float* ref_xy = (const float*)d_in[2];
  const float* Wv     = (const float*)d_in[3];
  const float* W_off  = (const float*)d_in[4];
  const float* b_off  = (const float*)d_in[5];
  const float* W_w    = (const float*)d_in[6];
  const float* b_w    = (const float*)d_in[7];
  const float* W_out  = (const float*)d_in[8];
  const float* b_out  = (const float*)d_in[9];
  float* out = (float*)d_out;

  // workspace (no aliasing; ~71 MB total)
  char* ws = (char*)d_ws;
  __hip_bfloat16* qsplit = (__hip_bfloat16*)ws; ws += (size_t)8192 * 1024 * 2;
  __hip_bfloat16* Wcat   = (__hip_bfloat16*)ws; ws += (size_t)384 * 1536 * 2;
  float* bias_cat        = (float*)ws;          ws += 384 * 4;
  float* projbuf         = (float*)ws;          ws += (size_t)8192 * 384 * 4;
  __hip_bfloat16* fmapT  = (__hip_bfloat16*)ws; ws += (size_t)4 * 4096 * 512 * 2;
  __hip_bfloat16* WvT    = (__hip_bfloat16*)ws; ws += (size_t)512 * 512 * 2;
  __hip_bfloat16* WoutT  = (__hip_bfloat16*)ws; ws += (size_t)512 * 512 * 2;
  __hip_bfloat16* vflat  = (__hip_bfloat16*)ws; ws += (size_t)4 * 8 * 4096 * 64 * 2;
  __hip_bfloat16* ctxb   = (__hip_bfloat16*)ws; ws += (size_t)8192 * 512 * 2;

  // 1) fused prep: q split, Wcat/bias, weight + fmap transposes
  prep_kernel<<<dim3(8576), 256, 0, stream>>>(
      q, qsplit, W_off, W_w, b_off, b_w, Wcat, bias_cat, Wv, WvT, W_out, WoutT,
      fmap, fmapT);

  // 2) fused GEMMs: proj (384 long blocks FIRST) + value projection (512)
  fused_gemm<<<dim3(896), 256, 0, stream>>>(
      qsplit, Wcat, bias_cat, projbuf, fmapT, WvT, vflat);

  // 3) fused softmax + position math + bilinear gather -> ctx bf16
  //    (wave-per-token: 2048 blocks x 4 waves)
  sample_kernel<<<dim3(2048), 256, 0, stream>>>(
      ref_xy, projbuf, (const uint2*)vflat, (uint2*)ctxb);

  // 4) output projection + bias -> fp32 out
  outproj_kernel<<<dim3(64, 4), 256, 0, stream>>>(ctxb, WoutT, b_out, out);
}

// Round 11
// 183.546 us; speedup vs baseline: 1.0461x; 1.0461x over previous
//
#include <hip/hip_runtime.h>
#include <hip/hip_bf16.h>
#include <math.h>

// Problem constants
constexpr int Bsz = 4, T = 2048, Hh = 8;
constexpr int HFi = 64, WFi = 64;
constexpr float RADIUS = 0.08f;

typedef __bf16 bf16x8 __attribute__((ext_vector_type(8)));
typedef float f32x4 __attribute__((ext_vector_type(4)));
typedef unsigned short u16x8 __attribute__((ext_vector_type(8)));

typedef const __attribute__((address_space(1))) void* gcptr;
typedef __attribute__((address_space(3))) void* lptr;

#define GLOAD_LDS16(g, l) \
  __builtin_amdgcn_global_load_lds((gcptr)(const void*)(g), (lptr)(void*)(l), 16, 0, 0)

union BU { __hip_bfloat16 b; unsigned short u; };

// ---------------------------------------------------------------------------
// Combined prep kernel (one dispatch for all input conditioning):
//  blocks [0,4096):     split q into hi/lo bf16 (qsplit[m][0:512]=hi,[512:1024]=lo)
//  blocks [4096,6400):  build Wcat (384x1536 B^T = [W_hi|W_hi|W_lo]) + bias_cat
//  blocks [6400,6528):  transpose Wv -> WvT, W_out -> WoutT (64x64 tiles)
//  blocks [6528,8576):  transpose fmap (B,512,4096) -> fmapT (B,4096,512) bf16
// ---------------------------------------------------------------------------
__global__ __launch_bounds__(256) void prep_kernel(
    const float* __restrict__ q, __hip_bfloat16* __restrict__ qsplit,
    const float* __restrict__ W_off, const float* __restrict__ W_w,
    const float* __restrict__ b_off, const float* __restrict__ b_w,
    __hip_bfloat16* __restrict__ Wcat, float* __restrict__ bias_cat,
    const float* __restrict__ Wv, __hip_bfloat16* __restrict__ WvT,
    const float* __restrict__ W_out, __hip_bfloat16* __restrict__ WoutT,
    const float* __restrict__ fmap, __hip_bfloat16* __restrict__ fmapT) {
  __shared__ float tile[64][65];
  const int blk = blockIdx.x;
  const int tid = threadIdx.x;
  if (blk < 4096) {
    const int idx = blk * 256 + tid;  // 8192*128
    const int m = idx >> 7, kq = (idx & 127) * 4;
    float4 v = *(const float4*)&q[(size_t)m * 512 + kq];
    union { __hip_bfloat16 b[4]; ushort4 u; } hi, lo;
    float f[4] = {v.x, v.y, v.z, v.w};
#pragma unroll
    for (int i = 0; i < 4; ++i) {
      hi.b[i] = __float2bfloat16(f[i]);
      lo.b[i] = __float2bfloat16(f[i] - __bfloat162float(hi.b[i]));
    }
    *(ushort4*)&qsplit[(size_t)m * 1024 + kq] = hi.u;
    *(ushort4*)&qsplit[(size_t)m * 1024 + 512 + kq] = lo.u;
    return;
  }
  if (blk < 6400) {
    const int idx = (blk - 4096) * 256 + tid;  // 384*1536 = 589824
    const int n = idx / 1536, kp = idx % 1536;
    const int k = kp & 511;
    const float w = (n < 256) ? W_off[(size_t)k * 256 + n]
                              : W_w[(size_t)k * 128 + (n - 256)];
    const __hip_bfloat16 h = __float2bfloat16(w);
    const __hip_bfloat16 o =
        (kp < 1024) ? h : __float2bfloat16(w - __bfloat162float(h));
    Wcat[(size_t)n * 1536 + kp] = o;
    if (idx < 384) bias_cat[idx] = (idx < 256) ? b_off[idx] : b_w[idx - 256];
    return;
  }
  // --- 64x64 transpose segments ---
  const float* src;
  __hip_bfloat16* dst;
  int ldin, ldout, r0, c0;
  if (blk < 6528) {
    const int t2 = blk - 6400;  // 0..127
    src = (t2 < 64) ? Wv : W_out;
    dst = (t2 < 64) ? WvT : WoutT;
    ldin = 512; ldout = 512;
    const int tl = t2 & 63;
    r0 = (tl >> 3) * 64; c0 = (tl & 7) * 64;
  } else {
    const int t3 = blk - 6528;          // 0..2047
    const int b = t3 >> 9;              // 512 tiles per batch
    const int tl = t3 & 511;
    r0 = (tl >> 6) * 64;                // channel rows
    c0 = (tl & 63) * 64;                // spatial cols
    src = fmap + (size_t)b * 512 * 4096;
    dst = fmapT + (size_t)b * 4096 * 512;
    ldin = 4096; ldout = 512;
  }
  {
    const int tr = tid >> 2;          // 0..63 input row
    const int tc = (tid & 3) * 16;    // input col chunk
    const float* s = &src[(size_t)(r0 + tr) * ldin + c0 + tc];
#pragma unroll
    for (int j4 = 0; j4 < 4; ++j4) {
      float4 v = *(const float4*)&s[j4 * 4];
      tile[tr][tc + j4 * 4 + 0] = v.x;
      tile[tr][tc + j4 * 4 + 1] = v.y;
      tile[tr][tc + j4 * 4 + 2] = v.z;
      tile[tr][tc + j4 * 4 + 3] = v.w;
    }
    __syncthreads();
    const int oc = tid >> 2;          // output row offset (= input col)
    const int rb = (tid & 3) * 16;    // output col chunk (= input rows)
    u16x8 o0, o1;
#pragma unroll
    for (int j = 0; j < 8; ++j) {
      BU a, bz;
      a.b = __float2bfloat16(tile[rb + j][oc]);
      bz.b = __float2bfloat16(tile[rb + 8 + j][oc]);
      o0[j] = a.u;
      o1[j] = bz.u;
    }
    __hip_bfloat16* d = &dst[(size_t)(c0 + oc) * ldout + r0 + rb];
    *(u16x8*)d = o0;
    *(u16x8*)(d + 8) = o1;
  }
}

// ---------------------------------------------------------------------------
// Fused GEMM dispatch (round-9 proven).
//  blocks [0,384):   offset/logit projection, 128x64 tile, K=1536 split-bf16.
//  blocks [384,896): value projection, 128x128 tile, per-batch, C retiled
//                    through LDS -> coalesced bf16 stores to vflat.
// LDS swizzle: LDS[r][c] holds global[r][c ^ ((r&7)*8)]; staging scol =
// ((lane&7)^srow)*8, fragment reads XOR (l15&7)*8 -> conflict-free b128.
// ---------------------------------------------------------------------------
__global__ __launch_bounds__(256) void fused_gemm(
    const __hip_bfloat16* __restrict__ qsplit,
    const __hip_bfloat16* __restrict__ Wcat,
    const float* __restrict__ bias_cat, float* __restrict__ projbuf,
    const __hip_bfloat16* __restrict__ fmapT,
    const __hip_bfloat16* __restrict__ WvT, __hip_bfloat16* __restrict__ vflat) {
  __shared__ unsigned short lds[2 * 128 * 64];  // As | Bs ; reused as C-tile
  unsigned short* As = lds;
  unsigned short* Bs = lds + 128 * 64;
  const int blk = blockIdx.x;
  const int tid = threadIdx.x;
  const int lane = tid & 63;
  const int wave = tid >> 6;
  const int l15 = lane & 15, quad = lane >> 4;
  const int srow = lane >> 3;                   // 0..7
  const int scol = (((lane & 7) ^ srow) * 8);   // swizzled source col (elems)
  const int fxor = (l15 & 7) * 8;               // fragment-read XOR (elems)

  if (blk < 384) {
    // ---- projection GEMM: 128x64, K=1536 ----
    const int m0 = (blk & 63) * 128;
    const int n0 = (blk >> 6) * 64;
    const int wm = (wave & 1) * 64, wn = (wave >> 1) * 32;
    f32x4 acc[4][2] = {};
    for (int k0 = 0; k0 < 1536; k0 += 64) {
      const int ka = (k0 >= 1024) ? k0 - 1024 : k0;
#pragma unroll
      for (int i = 0; i < 4; ++i) {
        const int j = wave * 4 + i;
        const int r = j * 8 + srow;
        GLOAD_LDS16(qsplit + (size_t)(m0 + r) * 1024 + ka + scol, As + j * 512);
      }
#pragma unroll
      for (int i = 0; i < 2; ++i) {
        const int j = wave * 2 + i;
        const int r = j * 8 + srow;
        GLOAD_LDS16(Wcat + (size_t)(n0 + r) * 1536 + k0 + scol, Bs + j * 512);
      }
      __syncthreads();
#pragma unroll
      for (int ks = 0; ks < 2; ++ks) {
        bf16x8 af[4], bfr[2];
#pragma unroll
        for (int i = 0; i < 4; ++i)
          af[i] = *(const bf16x8*)&As[(wm + i * 16 + l15) * 64 + ((ks * 32 + quad * 8) ^ fxor)];
#pragma unroll
        for (int j = 0; j < 2; ++j)
          bfr[j] = *(const bf16x8*)&Bs[(wn + j * 16 + l15) * 64 + ((ks * 32 + quad * 8) ^ fxor)];
#pragma unroll
        for (int i = 0; i < 4; ++i)
#pragma unroll
          for (int j = 0; j < 2; ++j)
            acc[i][j] = __builtin_amdgcn_mfma_f32_16x16x32_bf16(af[i], bfr[j], acc[i][j], 0, 0, 0);
      }
      __syncthreads();
    }
#pragma unroll
    for (int i = 0; i < 4; ++i) {
      const int mbase = m0 + wm + i * 16 + quad * 4;
#pragma unroll
      for (int j = 0; j < 2; ++j) {
        const int n = n0 + wn + j * 16 + l15;
        const float bb = bias_cat[n];
#pragma unroll
        for (int r = 0; r < 4; ++r)
          projbuf[(size_t)(mbase + r) * 384 + n] = acc[i][j][r] + bb;
      }
    }
  } else {
    // ---- value projection GEMM: 128x128, K=512 ----
    const int vb = blk - 384;
    const int b = vb >> 7, rr = vb & 127;
    const int m0 = (rr >> 2) * 128;
    const int n0 = (rr & 3) * 128;
    const __hip_bfloat16* A = fmapT + (size_t)b * 4096 * 512;
    __hip_bfloat16* vout = vflat + (size_t)b * 8 * 4096 * 64;
    const int wm = (wave & 1) * 64, wn = (wave >> 1) * 64;
    f32x4 acc[4][4] = {};
    for (int k0 = 0; k0 < 512; k0 += 64) {
#pragma unroll
      for (int i = 0; i < 4; ++i) {
        const int j = wave * 4 + i;
        const int r = j * 8 + srow;
        GLOAD_LDS16(A + (size_t)(m0 + r) * 512 + k0 + scol, As + j * 512);
        GLOAD_LDS16(WvT + (size_t)(n0 + r) * 512 + k0 + scol, Bs + j * 512);
      }
      __syncthreads();
#pragma unroll
      for (int ks = 0; ks < 2; ++ks) {
        bf16x8 af[4], bfr[4];
#pragma unroll
        for (int i = 0; i < 4; ++i)
          af[i] = *(const bf16x8*)&As[(wm + i * 16 + l15) * 64 + ((ks * 32 + quad * 8) ^ fxor)];
#pragma unroll
        for (int j = 0; j < 4; ++j)
          bfr[j] = *(const bf16x8*)&Bs[(wn + j * 16 + l15) * 64 + ((ks * 32 + quad * 8) ^ fxor)];
#pragma unroll
        for (int i = 0; i < 4; ++i)
#pragma unroll
          for (int j = 0; j < 4; ++j)
            acc[i][j] = __builtin_amdgcn_mfma_f32_16x16x32_bf16(af[i], bfr[j], acc[i][j], 0, 0, 0);
      }
      __syncthreads();
    }
    // epilogue: retile C through LDS (swizzled, conflict-free) -> u16x8 stores
    unsigned short* Ct = lds;  // [128][128] bf16
#pragma unroll
    for (int i = 0; i < 4; ++i) {
#pragma unroll
      for (int j = 0; j < 4; ++j) {
        const int ngl = wn + j * 16 + l15;
#pragma unroll
        for (int r = 0; r < 4; ++r) {
          const int sl = wm + i * 16 + quad * 4 + r;
          BU u;
          u.b = __float2bfloat16(acc[i][j][r]);
          Ct[sl * 128 + (ngl ^ (((sl >> 2) & 3) * 16))] = u.u;
        }
      }
    }
    __syncthreads();
#pragma unroll
    for (int c = 0; c < 8; ++c) {
      const int sl = (tid >> 4) + c * 16;
      const int chunk = tid & 15;
      const int head = (n0 >> 6) + (chunk >> 3);
      const int dh = (chunk & 7) * 8;
      const int e = (chunk * 8) ^ (((sl >> 2) & 3) * 16);
      *(u16x8*)(vout + (size_t)head * (4096 * 64) + (size_t)(m0 + sl) * 64 + dh) =
          *(const u16x8*)&Ct[sl * 128 + e];
    }
  }
}

// ---------------------------------------------------------------------------
// Fused softmax + position math + bilinear gather (round-9 proven version:
// block per token, VALU-saturated — wave-per-token variant regressed in R10).
// ---------------------------------------------------------------------------
__global__ __launch_bounds__(256) void sample_kernel(
    const float* __restrict__ ref_xy, const float* __restrict__ projbuf,
    const unsigned int* __restrict__ vflat2, unsigned int* __restrict__ ctx2) {
  __shared__ float4 wsm[8][16];  // {wx0, wx1, wy0*aw, wy1*aw}
  __shared__ int bsm[8][16];     // base dword index (yA*64+xA)*32
  const int blk = blockIdx.x;
  const int bt = (blk & 7) * 1024 + (blk >> 3);  // XCD-contiguous bt ranges
  const int b = bt >> 11;                        // T = 2048
  const int tid = threadIdx.x;
  const int wave = tid >> 6;
  const int lane = tid & 63;
  const int l31 = lane & 31;
  const bool hiHalf = lane >= 32;

  if (tid < 64) {
    const int h = tid >> 3, pi = tid & 7;
    const float ref_x = ref_xy[bt * 2 + 0];
    const float ref_y = ref_xy[bt * 2 + 1];
    const float* prow = projbuf + (size_t)bt * 384;
    const float* lg = prow + 256 + h * 16;
    float lv[16];
    float mx = -1e30f;
#pragma unroll
    for (int p = 0; p < 16; ++p) {
      lv[p] = lg[p];
      mx = fmaxf(mx, lv[p]);
    }
    float sum = 0.f;
#pragma unroll
    for (int p = 0; p < 16; ++p) {
      lv[p] = __expf(lv[p] - mx);
      sum += lv[p];
    }
    const float inv = 1.0f / sum;
    const float* of = prow + h * 32;
#pragma unroll
    for (int pq = 0; pq < 2; ++pq) {
      const int p = pi + pq * 8;
      const float aw = inv * lv[p];
      const float2 o2 = *(const float2*)&of[p * 2];
      const float ix = (ref_x + RADIUS * o2.x) * (float)(WFi - 1);
      const float iy = (ref_y + RADIUS * o2.y) * (float)(HFi - 1);
      const float ix0f = floorf(ix), iy0f = floorf(iy);
      const float fx = ix - ix0f, fy = iy - iy0f;
      const int ix0 = (int)ix0f, iy0 = (int)iy0f;

      float wx0 = 1.f - fx, wx1 = fx;
      float wy0 = 1.f - fy, wy1 = fy;
      if (ix0 == -1) { wx0 = fx; wx1 = 0.f; }
      if (ix0 == 63) { wx0 = 0.f; wx1 = 1.f - fx; }
      if (ix0 < -1 || ix0 > 63) { wx0 = 0.f; wx1 = 0.f; }
      if (iy0 == -1) { wy0 = fy; wy1 = 0.f; }
      if (iy0 == 63) { wy0 = 0.f; wy1 = 1.f - fy; }
      if (iy0 < -1 || iy0 > 63) { wy0 = 0.f; wy1 = 0.f; }
      const int xA = min(max(ix0, 0), WFi - 2);
      const int yA = min(max(iy0, 0), HFi - 2);

      wsm[h][p] = make_float4(wx0, wx1, wy0 * aw, wy1 * aw);
      bsm[h][p] = (yA * WFi + xA) * 32;
    }
  }
  __syncthreads();

  for (int h = wave; h < Hh; h += 4) {
    const float4* wq = &wsm[h][hiHalf ? 8 : 0];
    const int* bq = &bsm[h][hiHalf ? 8 : 0];
    const unsigned int* vb = vflat2 + (size_t)(b * 8 + h) * (4096 * 32) + l31;

    float acc0 = 0.f, acc1 = 0.f;
#pragma unroll
    for (int pp = 0; pp < 8; ++pp) {
      const float4 w4 = wq[pp];
      const unsigned int* r0 = vb + bq[pp];

      const unsigned int v00 = r0[0], v10 = r0[32];
      const unsigned int v01 = r0[2048], v11 = r0[2080];

      const float w00 = w4.x * w4.z, w10 = w4.y * w4.z;
      const float w01 = w4.x * w4.w, w11 = w4.y * w4.w;

      const float e00 = __uint_as_float(v00 << 16), o00 = __uint_as_float(v00 & 0xffff0000u);
      const float e10 = __uint_as_float(v10 << 16), o10 = __uint_as_float(v10 & 0xffff0000u);
      const float e01 = __uint_as_float(v01 << 16), o01 = __uint_as_float(v01 & 0xffff0000u);
      const float e11 = __uint_as_float(v11 << 16), o11 = __uint_as_float(v11 & 0xffff0000u);

      acc0 = fmaf(w00, e00, acc0);
      acc1 = fmaf(w00, o00, acc1);
      acc0 = fmaf(w10, e10, acc0);
      acc1 = fmaf(w10, o10, acc1);
      acc0 = fmaf(w01, e01, acc0);
      acc1 = fmaf(w01, o01, acc1);
      acc0 = fmaf(w11, e11, acc0);
      acc1 = fmaf(w11, o11, acc1);
    }

    acc0 += __shfl_xor(acc0, 32, 64);
    acc1 += __shfl_xor(acc1, 32, 64);
    if (!hiHalf) {
      BU c0, c1;
      c0.b = __float2bfloat16(acc0);
      c1.b = __float2bfloat16(acc1);
      ctx2[(size_t)bt * 256 + h * 32 + l31] = ((unsigned int)c1.u << 16) | c0.u;
    }
  }
}

// ---------------------------------------------------------------------------
// Output projection: 64x64 tiles, grid (128, 8) = 1024 blocks = 4 blocks/CU
// (vs 128x128 @ 256 blocks = 1/CU: no co-resident blocks to hide barrier
// drain). BK=64, global_load_lds(16B), swizzled LDS, 16 KB total.
// ---------------------------------------------------------------------------
__global__ __launch_bounds__(256) void outproj_kernel(
    const __hip_bfloat16* __restrict__ A, const __hip_bfloat16* __restrict__ Bm,
    const float* __restrict__ bias, float* __restrict__ C) {
  __shared__ unsigned short As[64 * 64];
  __shared__ unsigned short Bs[64 * 64];
  const int tid = threadIdx.x;
  const int lane = tid & 63;
  const int wave = tid >> 6;
  const int wm = (wave & 1) * 32, wn = (wave >> 1) * 32;
  const int l15 = lane & 15, quad = lane >> 4;
  const int m0 = blockIdx.x * 64, n0 = blockIdx.y * 64;
  const int srow = lane >> 3;
  const int scol = (((lane & 7) ^ srow) * 8);
  const int fxor = (l15 & 7) * 8;

  f32x4 acc[2][2] = {};

  for (int k0 = 0; k0 < 512; k0 += 64) {
#pragma unroll
    for (int i = 0; i < 2; ++i) {
      const int j = wave * 2 + i;          // chunk 0..7
      const int r = j * 8 + srow;          // row 0..63
      GLOAD_LDS16(A + (size_t)(m0 + r) * 512 + k0 + scol, As + j * 512);
      GLOAD_LDS16(Bm + (size_t)(n0 + r) * 512 + k0 + scol, Bs + j * 512);
    }
    __syncthreads();
#pragma unroll
    for (int ks = 0; ks < 2; ++ks) {
      bf16x8 af[2], bfr[2];
#pragma unroll
      for (int i = 0; i < 2; ++i)
        af[i] = *(const bf16x8*)&As[(wm + i * 16 + l15) * 64 + ((ks * 32 + quad * 8) ^ fxor)];
#pragma unroll
      for (int j = 0; j < 2; ++j)
        bfr[j] = *(const bf16x8*)&Bs[(wn + j * 16 + l15) * 64 + ((ks * 32 + quad * 8) ^ fxor)];
#pragma unroll
      for (int i = 0; i < 2; ++i)
#pragma unroll
        for (int j = 0; j < 2; ++j)
          acc[i][j] = __builtin_amdgcn_mfma_f32_16x16x32_bf16(af[i], bfr[j], acc[i][j], 0, 0, 0);
    }
    __syncthreads();
  }

#pragma unroll
  for (int i = 0; i < 2; ++i) {
    const int mbase = m0 + wm + i * 16 + quad * 4;
#pragma unroll
    for (int j = 0; j < 2; ++j) {
      const int n = n0 + wn + j * 16 + l15;
      const float bb = bias[n];
#pragma unroll
      for (int r = 0; r < 4; ++r)
        C[(size_t)(mbase + r) * 512 + n] = acc[i][j][r] + bb;
    }
  }
}

// ---------------------------------------------------------------------------
extern "C" void kernel_launch(void* const* d_in, const int* in_sizes, int n_in,
                              void* d_out, int out_size, void* d_ws, size_t ws_size,
                              hipStream_t stream) {
  const float* q      = (const float*)d_in[0];
  const float* fmap   = (const float*)d_in[1];
  const float* ref_xy = (const float*)d_in[2];
  const float* Wv     = (const float*)d_in[3];
  const float* W_off  = (const float*)d_in[4];
  const float* b_off  = (const float*)d_in[5];
  const float* W_w    = (const float*)d_in[6];
  const float* b_w    = (const float*)d_in[7];
  const float* W_out  = (const float*)d_in[8];
  const float* b_out  = (const float*)d_in[9];
  float* out = (float*)d_out;

  // workspace (no aliasing; ~71 MB total)
  char* ws = (char*)d_ws;
  __hip_bfloat16* qsplit = (__hip_bfloat16*)ws; ws += (size_t)8192 * 1024 * 2;
  __hip_bfloat16* Wcat   = (__hip_bfloat16*)ws; ws += (size_t)384 * 1536 * 2;
  float* bias_cat        = (float*)ws;          ws += 384 * 4;
  float* projbuf         = (float*)ws;          ws += (size_t)8192 * 384 * 4;
  __hip_bfloat16* fmapT  = (__hip_bfloat16*)ws; ws += (size_t)4 * 4096 * 512 * 2;
  __hip_bfloat16* WvT    = (__hip_bfloat16*)ws; ws += (size_t)512 * 512 * 2;
  __hip_bfloat16* WoutT  = (__hip_bfloat16*)ws; ws += (size_t)512 * 512 * 2;
  __hip_bfloat16* vflat  = (__hip_bfloat16*)ws; ws += (size_t)4 * 8 * 4096 * 64 * 2;
  __hip_bfloat16* ctxb   = (__hip_bfloat16*)ws; ws += (size_t)8192 * 512 * 2;

  // 1) fused prep: q split, Wcat/bias, weight + fmap transposes
  prep_kernel<<<dim3(8576), 256, 0, stream>>>(
      q, qsplit, W_off, W_w, b_off, b_w, Wcat, bias_cat, Wv, WvT, W_out, WoutT,
      fmap, fmapT);

  // 2) fused GEMMs: proj (384 long blocks FIRST) + value projection (512)
  fused_gemm<<<dim3(896), 256, 0, stream>>>(
      qsplit, Wcat, bias_cat, projbuf, fmapT, WvT, vflat);

  // 3) fused softmax + position math + bilinear gather -> ctx bf16
  sample_kernel<<<dim3(Bsz * T), 256, 0, stream>>>(
      ref_xy, projbuf, (const unsigned int*)vflat, (unsigned int*)ctxb);

  // 4) output projection + bias -> fp32 out (64x64 tiles, 4 blocks/CU)
  outproj_kernel<<<dim3(128, 8), 256, 0, stream>>>(ctxb, WoutT, b_out, out);
}